// Round 16
// baseline (1782.127 us; speedup 1.0000x reference)
//
#include <hip/hip_runtime.h>
#include <hip/hip_bf16.h>
#include <math.h>

#define B 32
#define S 512
#define W 8
#define CE 100       // CHAR_EMB
#define SE 100       // SUB_EMB
#define HD 200       // hidden per direction
#define G4 800       // 4*HD
#define IN2 200      // 2*CHAR_EMB
#define SUBV 100000
#define UNK 1
#define NL 4
#define SK (S - 2)   // 510
#define FEAT 500     // 2*HD + SE

__device__ __forceinline__ float fsig(float x) {
    return 1.f / (1.f + __expf(-x));
}
__device__ __forceinline__ float ftanh(float x) {
    float e = __expf(-2.f * fabsf(x));   // e in (0,1], overflow-safe
    float r = (1.f - e) / (1.f + e);
    return copysignf(r, x);
}

// 64-lane sum; result valid in lane 63. DPP adds run on the VALU pipe.
__device__ __forceinline__ float wave_sum64(float v) {
#if __has_builtin(__builtin_amdgcn_update_dpp)
#define DPPADD(C) { int x_ = __builtin_amdgcn_update_dpp(0, __float_as_int(v), C, 0xf, 0xf, true); \
                    v += __int_as_float(x_); }
    DPPADD(0x111)  // row_shr:1
    DPPADD(0x112)  // row_shr:2
    DPPADD(0x114)  // row_shr:4
    DPPADD(0x118)  // row_shr:8  -> lane15/31/47/63 hold row sums
    DPPADD(0x142)  // row_bcast15 -> lane31 = rows0+1, lane63 = rows2+3
    DPPADD(0x143)  // row_bcast31 -> lane63 = total
#undef DPPADD
    return v;
#else
    v += __shfl_xor(v, 1);  v += __shfl_xor(v, 2);  v += __shfl_xor(v, 4);
    v += __shfl_xor(v, 8);  v += __shfl_xor(v, 16); v += __shfl_xor(v, 32);
    return v;
#endif
}

// ---------------- K0: transpose [800][200] -> [200][800] ----------------
__global__ void transpose_k(const float* __restrict__ in, float* __restrict__ out) {
    int o = blockIdx.x * 256 + threadIdx.x;   // 160000 elements
    if (o >= IN2 * G4) return;
    int k = o / G4, g = o % G4;
    out[o] = in[g * 200 + k];
}

// ---------------- K0b: f32 -> packed bf16 (RNE), pairwise ----------------
__global__ void cvt_bf16_k(const float* __restrict__ in, unsigned* __restrict__ out,
                           int n2) {
    int i = blockIdx.x * 256 + threadIdx.x;   // pair index
    if (i >= n2) return;
    unsigned a = __float_as_uint(in[2 * i]);
    unsigned b = __float_as_uint(in[2 * i + 1]);
    a = (a + 0x7fffu + ((a >> 16) & 1u)) >> 16;
    b = (b + 0x7fffu + ((b >> 16) & 1u)) >> 16;
    out[i] = a | (b << 16);
}

// ---------------- K1: embedding concat -> x[B][S][200] ----------------
__global__ void embed_k(const int* __restrict__ chars, const int* __restrict__ bichars,
                        const float* __restrict__ cw, const float* __restrict__ bw,
                        float* __restrict__ x) {
    int t = blockIdx.x * 256 + threadIdx.x;
    if (t >= B * S * IN2) return;
    int c = t % IN2;
    int row = t / IN2;
    float v;
    if (c < CE) v = cw[(size_t)chars[row] * CE + c];
    else        v = bw[(size_t)bichars[row] * CE + (c - CE)];
    x[t] = v;
}

// ---------------- K2: xg = x @ WihT + b (both directions) ----------------
__global__ void xg_k(const float* __restrict__ x,
                     const float* __restrict__ WihT_f, const float* __restrict__ bf,
                     const float* __restrict__ WihT_b, const float* __restrict__ bb,
                     float* __restrict__ xgf, float* __restrict__ xgb) {
    const int dir = blockIdx.y;
    const float* WT   = dir ? WihT_b : WihT_f;
    const float* bias = dir ? bb : bf;
    float* out        = dir ? xgb : xgf;
    int r0 = blockIdx.x * 16;
    __shared__ float xs[16][IN2];
    for (int i = threadIdx.x; i < 16 * IN2; i += 256) {
        xs[i / IN2][i % IN2] = x[(size_t)(r0 + i / IN2) * IN2 + i % IN2];
    }
    __syncthreads();
    float acc[4][16];
    for (int q = 0; q < 4; q++)
        for (int r = 0; r < 16; r++) acc[q][r] = 0.f;
    int tid = threadIdx.x;
    for (int k = 0; k < IN2; k++) {
        const float* wrow = WT + (size_t)k * G4;
        float w0 = wrow[tid];
        float w1 = wrow[tid + 256];
        float w2 = wrow[tid + 512];
        float w3 = (tid < 32) ? wrow[tid + 768] : 0.f;
        for (int r = 0; r < 16; r++) {
            float xv = xs[r][k];
            acc[0][r] += w0 * xv;
            acc[1][r] += w1 * xv;
            acc[2][r] += w2 * xv;
            acc[3][r] += w3 * xv;
        }
    }
    for (int q = 0; q < 4; q++) {
        int g = tid + q * 256;
        if (g < G4) {
            float bv = bias[g];
            for (int r = 0; r < 16; r++)
                out[(size_t)(r0 + r) * G4 + g] = acc[q][r] + bv;
        }
    }
}

// ---------------- K3: LSTM recurrence, bf16 weights in LDS ---------------
// r13 schedule unchanged (2 superphases/step, 1 barrier each: act-first ->
// compute -> fill-poll). Whh slice in LDS as bf16: one column read is
// ds_read_b64 (vs b128 in r13) — halves the LDS-issue cost that bound r13.
// DEADLOCK FIX (r15 post-mortem): DOTCOL reads slots up to 99*50+63 = 5013;
// staging now initializes [0,5120) with slots >=5000 ZEROED, so lanes>=50
// never read uninitialized LDS (NaN there propagated into h and hung the
// NaN-sentinel polls). ldsf sized 21000 floats (84000B) to pin 1 block/CU.
__global__ __launch_bounds__(1024)
void lstm_k(const float* __restrict__ xgf, const float* __restrict__ xgb,
            const unsigned* __restrict__ whhbf_f, const unsigned* __restrict__ whhbf_b,
            float* __restrict__ hf, float* __restrict__ hb) {
    __shared__ __align__(16) float ldsf[21000];   // 84000 B total
    // float offsets: [0,10240) bf16 weights as 5120 uint2 (>=5000 zeroed);
    // hsA @10240, hsB @10496, gbA @10752, gbB @10880; tail = packing pad.
    unsigned* wbf = (unsigned*)ldsf;
    float* hsA  = ldsf + 10240;
    float* hsB  = ldsf + 10496;
    float* gbA  = ldsf + 10752;
    float* gbB  = ldsf + 10880;

    const int blk = blockIdx.x;
    const int sl  = blk >> 5;                     // slice 0..7 (25 units)
    const int pg  = blk & 31;                     // dir*16 + pair
    const int dir = pg >> 4;
    const int bA  = pg & 15;
    const int bB  = bA + 16;
    const float* xg      = dir ? xgb : xgf;
    const unsigned* whbf = dir ? whhbf_b : whhbf_f;
    float* hout          = dir ? hb : hf;

    const int t = threadIdx.x;
    const int lane = t & 63;
    const int wid = t >> 6;                       // wave id 0..15

    // stage bf16 weights: uint2 slot i = col*50+l holds Whh[row(col)][4l..4l+3]
    // col = gate*25+unit -> row = gate*200 + sl*25 + unit.
    // Slots [5000,5120): ZERO (read by lanes>=50 at high cols; hv=0 there,
    // but the bits must be finite — uninitialized LDS caused r15's hang).
    for (int i = t; i < 5120; i += 1024) {
        uint2 v = {0u, 0u};
        if (i < 5000) {
            int col = i / 50, l = i - col * 50;
            int row = (col / 25) * 200 + sl * 25 + (col % 25);
            v = ((const uint2*)whbf)[row * 50 + l];
        }
        ((uint2*)wbf)[i] = v;
    }
    if (t < 256) { hsA[t] = 0.f; hsB[t] = 0.f; }

    const bool is_act = (t >= 960) && (t < 985);  // wave 15, lanes 0..24
    const int u = t - 960;
    const bool fill = (t < 200) && (t / 25 != sl);
    float cstA = 0.f, cstB = 0.f;
    float xA0=0,xA1=0,xA2=0,xA3=0, xB0=0,xB1=0,xB2=0,xB3=0;
    if (is_act) {
        int ts0 = dir ? (S - 1) : 0;
        const float* pa = xg + ((size_t)bA * S + ts0) * G4 + sl * 25 + u;
        const float* pb = xg + ((size_t)bB * S + ts0) * G4 + sl * 25 + u;
        xA0 = pa[0]; xA1 = pa[200]; xA2 = pa[400]; xA3 = pa[600];
        xB0 = pb[0]; xB1 = pb[200]; xB2 = pb[400]; xB3 = pb[600];
    }
    __syncthreads();

    // per column: 1 ds_read_b64 + 4 unpack (shift/and) + 4 fma + DPP reduce.
#define DOTCOL(c, hv, out_a)                                                   \
    {                                                                          \
        uint2 wv = ((const uint2*)wbf)[(c) * 50 + lane];                       \
        float w0 = __uint_as_float(wv.x << 16);                                \
        float w1 = __uint_as_float(wv.x & 0xffff0000u);                        \
        float w2 = __uint_as_float(wv.y << 16);                                \
        float w3 = __uint_as_float(wv.y & 0xffff0000u);                        \
        float d = fmaf(w3, hv.w, fmaf(w2, hv.z, fmaf(w1, hv.y, w0 * hv.x)));   \
        out_a = wave_sum64(d);                                                 \
    }

#define COMPUTE(hsX, gbX)                                                      \
    {                                                                          \
        float4 hv = ((const float4*)hsX)[lane];                                \
        float a0, a1, a2, a3, a4, a5, a6 = 0.f;                                \
        DOTCOL(wid,      hv, a0)                                               \
        DOTCOL(wid + 15, hv, a1)                                               \
        DOTCOL(wid + 30, hv, a2)                                               \
        DOTCOL(wid + 45, hv, a3)                                               \
        DOTCOL(wid + 60, hv, a4)                                               \
        DOTCOL(wid + 75, hv, a5)                                               \
        if (wid < 10) DOTCOL(wid + 90, hv, a6)                                 \
        if (lane == 63) {                                                      \
            gbX[wid] = a0;      gbX[wid + 15] = a1; gbX[wid + 30] = a2;        \
            gbX[wid + 45] = a3; gbX[wid + 60] = a4; gbX[wid + 75] = a5;        \
            if (wid < 10) gbX[wid + 90] = a6;                                  \
        }                                                                      \
    }

#define POLL(dst, srcp)                                                        \
    {                                                                          \
        float v_;                                                              \
        do { v_ = __hip_atomic_load(srcp, __ATOMIC_RELAXED,                    \
                                    __HIP_MEMORY_SCOPE_AGENT); } while (v_ != v_); \
        dst = v_;                                                              \
    }

    for (int s = 0; s < S; s++) {
        const int ts  = dir ? (S - 1 - s) : s;          // time of step s
        const int tsp = dir ? (S - s)     : (s - 1);    // time of step s-1
        const int tsn = (s + 1 < S) ? (dir ? (S - 2 - s) : (s + 1)) : ts;

        // ======== SP0: act B(s-1) | compute A(s) | fill hsB <- h_B(s-1) ====
        if (is_act && s > 0) {
            float ig = fsig(gbB[u] + xB0);
            float fg = fsig(gbB[25 + u] + xB1);
            float gt = ftanh(gbB[50 + u] + xB2);
            float og = fsig(gbB[75 + u] + xB3);
            cstB = fg * cstB + ig * gt;
            float h = og * ftanh(cstB);
            hsB[sl * 25 + u] = h;
            __hip_atomic_store(&hout[((size_t)bB * S + tsp) * HD + sl * 25 + u], h,
                               __ATOMIC_RELAXED, __HIP_MEMORY_SCOPE_AGENT);
            const float* pn = xg + ((size_t)bB * S + ts) * G4 + sl * 25 + u;
            xB0 = pn[0]; xB1 = pn[200]; xB2 = pn[400]; xB3 = pn[600];
        }
        if (wid < 15) COMPUTE(hsA, gbA)
        if (s > 0 && fill) POLL(hsB[t], hout + ((size_t)bB * S + tsp) * HD + t)
        __syncthreads();

        // ======== SP1: act A(s) | compute B(s) | fill hsA <- h_A(s) ========
        if (is_act) {
            float ig = fsig(gbA[u] + xA0);
            float fg = fsig(gbA[25 + u] + xA1);
            float gt = ftanh(gbA[50 + u] + xA2);
            float og = fsig(gbA[75 + u] + xA3);
            cstA = fg * cstA + ig * gt;
            float h = og * ftanh(cstA);
            hsA[sl * 25 + u] = h;
            __hip_atomic_store(&hout[((size_t)bA * S + ts) * HD + sl * 25 + u], h,
                               __ATOMIC_RELAXED, __HIP_MEMORY_SCOPE_AGENT);
            const float* pn = xg + ((size_t)bA * S + tsn) * G4 + sl * 25 + u;
            xA0 = pn[0]; xA1 = pn[200]; xA2 = pn[400]; xA3 = pn[600];
        }
        if (wid < 15) COMPUTE(hsB, gbB)
        if (fill) POLL(hsA[t], hout + ((size_t)bA * S + ts) * HD + t)
        __syncthreads();
    }
    // epilogue: act B(S-1) (gbB from SP1(S-1), xB prefetched in SP0(S-1))
    if (is_act) {
        const int tl = dir ? 0 : (S - 1);
        float ig = fsig(gbB[u] + xB0);
        float fg = fsig(gbB[25 + u] + xB1);
        float gt = ftanh(gbB[50 + u] + xB2);
        float og = fsig(gbB[75 + u] + xB3);
        cstB = fg * cstB + ig * gt;
        float h = og * ftanh(cstB);
        __hip_atomic_store(&hout[((size_t)bB * S + tl) * HD + sl * 25 + u], h,
                           __ATOMIC_RELAXED, __HIP_MEMORY_SCOPE_AGENT);
    }
#undef COMPUTE
#undef DOTCOL
#undef POLL
}

// ---------------- K4: span features + subword emb + FFN ----------------
__global__ void out_k(const int* __restrict__ subwords,
                      const float* __restrict__ pre_w, const float* __restrict__ sub_w,
                      const float* __restrict__ hf, const float* __restrict__ hb,
                      const float* __restrict__ ffn_w, const float* __restrict__ ffn_b,
                      float* __restrict__ out) {
    int wave = (blockIdx.x * 256 + threadIdx.x) >> 6;
    int lane = threadIdx.x & 63;
    if (wave >= B * SK * W) return;
    int i = wave % W;
    int bk = wave / W;
    int k = bk % SK;
    int b = bk / SK;
    int end = k + i;
    float vscale = (end <= S - 3) ? 1.f : 0.f;
    int e1 = min(end + 1, S - 1);
    int e2 = min(end + 2, S - 1);
    const float* hfb = hf + (size_t)b * S * HD;
    const float* hbb = hb + (size_t)b * S * HD;
    int sw = subwords[wave];
    int sw2 = (sw >= SUBV) ? UNK : sw;
    float acc0 = 0, acc1 = 0, acc2 = 0, acc3 = 0;
    for (int j = lane; j < FEAT; j += 64) {
        float fv;
        if (j < HD) {
            fv = (hfb[(size_t)e1 * HD + j] - hfb[(size_t)k * HD + j]) * vscale;
        } else if (j < 2 * HD) {
            int jj = j - HD;
            fv = (hbb[(size_t)(k + 1) * HD + jj] - hbb[(size_t)e2 * HD + jj]) * vscale;
        } else {
            int jj = j - 2 * HD;
            fv = pre_w[(size_t)sw * SE + jj] + sub_w[(size_t)sw2 * SE + jj];
        }
        acc0 += ffn_w[j] * fv;
        acc1 += ffn_w[FEAT + j] * fv;
        acc2 += ffn_w[2 * FEAT + j] * fv;
        acc3 += ffn_w[3 * FEAT + j] * fv;
    }
    for (int off = 32; off; off >>= 1) {
        acc0 += __shfl_down(acc0, off);
        acc1 += __shfl_down(acc1, off);
        acc2 += __shfl_down(acc2, off);
        acc3 += __shfl_down(acc3, off);
    }
    if (lane == 0) {
        float* o = out + (size_t)wave * NL;
        o[0] = acc0 + ffn_b[0];
        o[1] = acc1 + ffn_b[1];
        o[2] = acc2 + ffn_b[2];
        o[3] = acc3 + ffn_b[3];
    }
}

extern "C" void kernel_launch(void* const* d_in, const int* in_sizes, int n_in,
                              void* d_out, int out_size, void* d_ws, size_t ws_size,
                              hipStream_t stream) {
    const int*   chars    = (const int*)d_in[0];
    const int*   bichars  = (const int*)d_in[1];
    const int*   subwords = (const int*)d_in[2];
    const float* cw    = (const float*)d_in[3];
    const float* bw    = (const float*)d_in[4];
    const float* subw  = (const float*)d_in[5];
    const float* prew  = (const float*)d_in[6];
    const float* Wih_f = (const float*)d_in[7];
    const float* Whh_f = (const float*)d_in[8];
    const float* b_f   = (const float*)d_in[9];
    const float* Wih_b = (const float*)d_in[10];
    const float* Whh_b = (const float*)d_in[11];
    const float* b_b   = (const float*)d_in[12];
    const float* ffn_w = (const float*)d_in[13];
    const float* ffn_b = (const float*)d_in[14];
    float* out = (float*)d_out;

    float* ws = (float*)d_ws;
    float* WihT_f = ws;                      // 160000 floats each
    float* WihT_b = WihT_f + 160000;
    float* x   = WihT_b + 160000;            // 3,276,800 floats
    float* xgf = x + 3276800;                // 13,107,200
    float* xgb = xgf + 13107200;             // 13,107,200
    float* hf  = xgb + 13107200;             // 3,276,800
    float* hb  = hf + 3276800;               // 3,276,800
    // bf16 weights REUSE the x region (free after xg_k) — keeps the total
    // workspace footprint identical to r13/r14. cvt runs after xg_k.
    unsigned* wbf_f = (unsigned*)x;          // 80,000 uints each
    unsigned* wbf_b = wbf_f + 80000;

    // NaN-fill h buffers: the data word itself is the readiness flag.
    (void)hipMemsetAsync(hf, 0xFF, 3276800 * sizeof(float), stream);
    (void)hipMemsetAsync(hb, 0xFF, 3276800 * sizeof(float), stream);
    transpose_k<<<625, 256, 0, stream>>>(Wih_f, WihT_f);
    transpose_k<<<625, 256, 0, stream>>>(Wih_b, WihT_b);
    embed_k<<<(B * S * IN2 + 255) / 256, 256, 0, stream>>>(chars, bichars, cw, bw, x);
    xg_k<<<dim3(B * S / 16, 2), 256, 0, stream>>>(x, WihT_f, b_f, WihT_b, b_b, xgf, xgb);
    cvt_bf16_k<<<313, 256, 0, stream>>>(Whh_f, wbf_f, 80000);
    cvt_bf16_k<<<313, 256, 0, stream>>>(Whh_b, wbf_b, 80000);
    lstm_k<<<256, 1024, 0, stream>>>(xgf, xgb, wbf_f, wbf_b, hf, hb);
    out_k<<<(B * SK * W) / 4, 256, 0, stream>>>(subwords, prew, subw, hf, hb, ffn_w, ffn_b, out);
}

// Round 17
// 1240.253 us; speedup vs baseline: 1.4369x; 1.4369x over previous
//
#include <hip/hip_runtime.h>
#include <hip/hip_bf16.h>
#include <math.h>

#define B 32
#define S 512
#define W 8
#define CE 100       // CHAR_EMB
#define SE 100       // SUB_EMB
#define HD 200       // hidden per direction
#define G4 800       // 4*HD
#define IN2 200      // 2*CHAR_EMB
#define SUBV 100000
#define UNK 1
#define NL 4
#define SK (S - 2)   // 510
#define FEAT 500     // 2*HD + SE

__device__ __forceinline__ float fsig(float x) {
    return 1.f / (1.f + __expf(-x));
}
__device__ __forceinline__ float ftanh(float x) {
    float e = __expf(-2.f * fabsf(x));   // e in (0,1], overflow-safe
    float r = (1.f - e) / (1.f + e);
    return copysignf(r, x);
}

// 64-lane sum; result valid in lane 63. DPP adds run on the VALU pipe.
__device__ __forceinline__ float wave_sum64(float v) {
#if __has_builtin(__builtin_amdgcn_update_dpp)
#define DPPADD(C) { int x_ = __builtin_amdgcn_update_dpp(0, __float_as_int(v), C, 0xf, 0xf, true); \
                    v += __int_as_float(x_); }
    DPPADD(0x111)  // row_shr:1
    DPPADD(0x112)  // row_shr:2
    DPPADD(0x114)  // row_shr:4
    DPPADD(0x118)  // row_shr:8  -> lane15/31/47/63 hold row sums
    DPPADD(0x142)  // row_bcast15 -> lane31 = rows0+1, lane63 = rows2+3
    DPPADD(0x143)  // row_bcast31 -> lane63 = total
#undef DPPADD
    return v;
#else
    v += __shfl_xor(v, 1);  v += __shfl_xor(v, 2);  v += __shfl_xor(v, 4);
    v += __shfl_xor(v, 8);  v += __shfl_xor(v, 16); v += __shfl_xor(v, 32);
    return v;
#endif
}

__device__ __forceinline__ float dot4(float4 w, float4 h) {
    return fmaf(w.w, h.w, fmaf(w.z, h.z, fmaf(w.y, h.y, w.x * h.x)));
}

// ---------------- K0: transpose [800][200] -> [200][800] ----------------
__global__ void transpose_k(const float* __restrict__ in, float* __restrict__ out) {
    int o = blockIdx.x * 256 + threadIdx.x;   // 160000 elements
    if (o >= IN2 * G4) return;
    int k = o / G4, g = o % G4;
    out[o] = in[g * 200 + k];
}

// ---------------- K2: fused embed + xg = emb(x) @ WihT + b ---------------
// Stages the 16-row x-tile by gathering char/bichar embeddings directly
// (no intermediate x buffer, no separate embed kernel).
__global__ void xg_k(const int* __restrict__ chars, const int* __restrict__ bichars,
                     const float* __restrict__ cw, const float* __restrict__ bw,
                     const float* __restrict__ WihT_f, const float* __restrict__ bf,
                     const float* __restrict__ WihT_b, const float* __restrict__ bb,
                     float* __restrict__ xgf, float* __restrict__ xgb) {
    const int dir = blockIdx.y;
    const float* WT   = dir ? WihT_b : WihT_f;
    const float* bias = dir ? bb : bf;
    float* out        = dir ? xgb : xgf;
    int r0 = blockIdx.x * 16;
    __shared__ float xs[16][IN2];
    for (int i = threadIdx.x; i < 16 * IN2; i += 256) {
        int r = i / IN2, c = i % IN2;
        int row = r0 + r;                         // flat token index b*S+s
        float v;
        if (c < CE) v = cw[(size_t)chars[row] * CE + c];
        else        v = bw[(size_t)bichars[row] * CE + (c - CE)];
        xs[r][c] = v;
    }
    __syncthreads();
    float acc[4][16];
    for (int q = 0; q < 4; q++)
        for (int r = 0; r < 16; r++) acc[q][r] = 0.f;
    int tid = threadIdx.x;
    for (int k = 0; k < IN2; k++) {
        const float* wrow = WT + (size_t)k * G4;
        float w0 = wrow[tid];
        float w1 = wrow[tid + 256];
        float w2 = wrow[tid + 512];
        float w3 = (tid < 32) ? wrow[tid + 768] : 0.f;
        for (int r = 0; r < 16; r++) {
            float xv = xs[r][k];
            acc[0][r] += w0 * xv;
            acc[1][r] += w1 * xv;
            acc[2][r] += w2 * xv;
            acc[3][r] += w3 * xv;
        }
    }
    for (int q = 0; q < 4; q++) {
        int g = tid + q * 256;
        if (g < G4) {
            float bv = bias[g];
            for (int r = 0; r < 16; r++)
                out[(size_t)(r0 + r) * G4 + g] = acc[q][r] + bv;
        }
    }
}

// ---------------- K3: LSTM recurrence, merged 2-barrier superphases ------
// EXACT r13 structure (981us proven): grid = 256 blocks = 8 slices x
// (2 dirs x 16 pairs); blk = sl*32 + pg keeps all 8 slices of a pair-chain
// on one XCD (XCD = blk%8 = pg%8). T=1024. Per step: TWO superphases, ONE
// barrier each.
//  SP0(s): wave15 acts B(s-1) FIRST (h store early in phase); waves 0-14
//          compute A(s) dense from hsA; fill lanes (t<200, foreign slice)
//          poll h_B(s-1) AFTER their compute. One barrier.
//  SP1(s): symmetric: act A(s); compute B(s); fill h_A(s) -> hsA for s+1.
// Data-flag sync: hout NaN-filled per launch; write-once addresses.
__global__ __launch_bounds__(1024)
void lstm_k(const float* __restrict__ xgf, const float* __restrict__ xgb,
            const float* __restrict__ Whh_f, const float* __restrict__ Whh_b,
            float* __restrict__ hf, float* __restrict__ hb) {
    __shared__ float4 wlds[5064];                 // [col*50+l]; pad for lane>=50
    __shared__ __align__(16) float hsA[256];
    __shared__ __align__(16) float hsB[256];
    __shared__ __align__(16) float gbA[112];      // [gate*25 + unit]
    __shared__ __align__(16) float gbB[112];

    const int blk = blockIdx.x;
    const int sl  = blk >> 5;                     // slice 0..7 (25 units)
    const int pg  = blk & 31;                     // dir*16 + pair
    const int dir = pg >> 4;
    const int bA  = pg & 15;
    const int bB  = bA + 16;
    const float* xg  = dir ? xgb : xgf;
    const float* Whh = dir ? Whh_b : Whh_f;
    float* hout      = dir ? hb : hf;

    const int t = threadIdx.x;
    const int lane = t & 63;
    const int wid = t >> 6;                       // wave id 0..15

    // stage weights: wlds[col*50+l] = Whh[row(col)][4l..4l+3]
    // col = gate*25+unit -> row = gate*200 + sl*25 + unit.
    // Slots [5000,5064): ZEROED so lane>=50 over-reads are finite (the r15
    // hang came from NaN bits in uninitialized LDS reaching the polls).
    for (int i = t; i < 5064; i += 1024) {
        float4 v = {0.f, 0.f, 0.f, 0.f};
        if (i < 5000) {
            int col = i / 50, l = i - col * 50;
            int row = (col / 25) * 200 + sl * 25 + (col % 25);
            v = *(const float4*)(Whh + (size_t)row * HD + 4 * l);
        }
        wlds[i] = v;
    }
    if (t < 256) { hsA[t] = 0.f; hsB[t] = 0.f; }

    const bool is_act = (t >= 960) && (t < 985);  // wave 15, lanes 0..24
    const int u = t - 960;
    const bool fill = (t < 200) && (t / 25 != sl);
    float cstA = 0.f, cstB = 0.f;
    float xA0=0,xA1=0,xA2=0,xA3=0, xB0=0,xB1=0,xB2=0,xB3=0;
    if (is_act) {
        int ts0 = dir ? (S - 1) : 0;
        const float* pa = xg + ((size_t)bA * S + ts0) * G4 + sl * 25 + u;
        const float* pb = xg + ((size_t)bB * S + ts0) * G4 + sl * 25 + u;
        xA0 = pa[0]; xA1 = pa[200]; xA2 = pa[400]; xA3 = pa[600];
        xB0 = pb[0]; xB1 = pb[200]; xB2 = pb[400]; xB3 = pb[600];
    }
    __syncthreads();

#define COMPUTE(hsX, gbX)                                                      \
    {                                                                          \
        float4 hv = ((const float4*)hsX)[lane];                                \
        _Pragma("unroll")                                                      \
        for (int j = 0; j < 7; j++) {                                          \
            int c = wid + 15 * j;                                              \
            if (c < 100) {                                                     \
                float4 wv = wlds[c * 50 + lane];                               \
                float a = wave_sum64(dot4(wv, hv));                            \
                if (lane == 63) gbX[c] = a;                                    \
            }                                                                  \
        }                                                                      \
    }

#define POLL(dst, srcp)                                                        \
    {                                                                          \
        float v_;                                                              \
        do { v_ = __hip_atomic_load(srcp, __ATOMIC_RELAXED,                    \
                                    __HIP_MEMORY_SCOPE_AGENT); } while (v_ != v_); \
        dst = v_;                                                              \
    }

    for (int s = 0; s < S; s++) {
        const int ts  = dir ? (S - 1 - s) : s;          // time of step s
        const int tsp = dir ? (S - s)     : (s - 1);    // time of step s-1
        const int tsn = (s + 1 < S) ? (dir ? (S - 2 - s) : (s + 1)) : ts;

        // ======== SP0: act B(s-1) | compute A(s) | fill hsB <- h_B(s-1) ====
        if (is_act && s > 0) {
            float ig = fsig(gbB[u] + xB0);
            float fg = fsig(gbB[25 + u] + xB1);
            float gt = ftanh(gbB[50 + u] + xB2);
            float og = fsig(gbB[75 + u] + xB3);
            cstB = fg * cstB + ig * gt;
            float h = og * ftanh(cstB);
            hsB[sl * 25 + u] = h;
            __hip_atomic_store(&hout[((size_t)bB * S + tsp) * HD + sl * 25 + u], h,
                               __ATOMIC_RELAXED, __HIP_MEMORY_SCOPE_AGENT);
            const float* pn = xg + ((size_t)bB * S + ts) * G4 + sl * 25 + u;
            xB0 = pn[0]; xB1 = pn[200]; xB2 = pn[400]; xB3 = pn[600];
        }
        if (wid < 15) COMPUTE(hsA, gbA)
        if (s > 0 && fill) POLL(hsB[t], hout + ((size_t)bB * S + tsp) * HD + t)
        __syncthreads();

        // ======== SP1: act A(s) | compute B(s) | fill hsA <- h_A(s) ========
        if (is_act) {
            float ig = fsig(gbA[u] + xA0);
            float fg = fsig(gbA[25 + u] + xA1);
            float gt = ftanh(gbA[50 + u] + xA2);
            float og = fsig(gbA[75 + u] + xA3);
            cstA = fg * cstA + ig * gt;
            float h = og * ftanh(cstA);
            hsA[sl * 25 + u] = h;
            __hip_atomic_store(&hout[((size_t)bA * S + ts) * HD + sl * 25 + u], h,
                               __ATOMIC_RELAXED, __HIP_MEMORY_SCOPE_AGENT);
            const float* pn = xg + ((size_t)bA * S + tsn) * G4 + sl * 25 + u;
            xA0 = pn[0]; xA1 = pn[200]; xA2 = pn[400]; xA3 = pn[600];
        }
        if (wid < 15) COMPUTE(hsB, gbB)
        if (fill) POLL(hsA[t], hout + ((size_t)bA * S + ts) * HD + t)
        __syncthreads();
    }
    // epilogue: act B(S-1) (gbB from SP1(S-1), xB prefetched in SP0(S-1))
    if (is_act) {
        const int tl = dir ? 0 : (S - 1);
        float ig = fsig(gbB[u] + xB0);
        float fg = fsig(gbB[25 + u] + xB1);
        float gt = ftanh(gbB[50 + u] + xB2);
        float og = fsig(gbB[75 + u] + xB3);
        cstB = fg * cstB + ig * gt;
        float h = og * ftanh(cstB);
        __hip_atomic_store(&hout[((size_t)bB * S + tl) * HD + sl * 25 + u], h,
                           __ATOMIC_RELAXED, __HIP_MEMORY_SCOPE_AGENT);
    }
#undef COMPUTE
#undef POLL
}

// ---------------- K4: span features + subword emb + FFN ----------------
__global__ void out_k(const int* __restrict__ subwords,
                      const float* __restrict__ pre_w, const float* __restrict__ sub_w,
                      const float* __restrict__ hf, const float* __restrict__ hb,
                      const float* __restrict__ ffn_w, const float* __restrict__ ffn_b,
                      float* __restrict__ out) {
    int wave = (blockIdx.x * 256 + threadIdx.x) >> 6;
    int lane = threadIdx.x & 63;
    if (wave >= B * SK * W) return;
    int i = wave % W;
    int bk = wave / W;
    int k = bk % SK;
    int b = bk / SK;
    int end = k + i;
    float vscale = (end <= S - 3) ? 1.f : 0.f;
    int e1 = min(end + 1, S - 1);
    int e2 = min(end + 2, S - 1);
    const float* hfb = hf + (size_t)b * S * HD;
    const float* hbb = hb + (size_t)b * S * HD;
    int sw = subwords[wave];
    int sw2 = (sw >= SUBV) ? UNK : sw;
    float acc0 = 0, acc1 = 0, acc2 = 0, acc3 = 0;
    for (int j = lane; j < FEAT; j += 64) {
        float fv;
        if (j < HD) {
            fv = (hfb[(size_t)e1 * HD + j] - hfb[(size_t)k * HD + j]) * vscale;
        } else if (j < 2 * HD) {
            int jj = j - HD;
            fv = (hbb[(size_t)(k + 1) * HD + jj] - hbb[(size_t)e2 * HD + jj]) * vscale;
        } else {
            int jj = j - 2 * HD;
            fv = pre_w[(size_t)sw * SE + jj] + sub_w[(size_t)sw2 * SE + jj];
        }
        acc0 += ffn_w[j] * fv;
        acc1 += ffn_w[FEAT + j] * fv;
        acc2 += ffn_w[2 * FEAT + j] * fv;
        acc3 += ffn_w[3 * FEAT + j] * fv;
    }
    for (int off = 32; off; off >>= 1) {
        acc0 += __shfl_down(acc0, off);
        acc1 += __shfl_down(acc1, off);
        acc2 += __shfl_down(acc2, off);
        acc3 += __shfl_down(acc3, off);
    }
    if (lane == 0) {
        float* o = out + (size_t)wave * NL;
        o[0] = acc0 + ffn_b[0];
        o[1] = acc1 + ffn_b[1];
        o[2] = acc2 + ffn_b[2];
        o[3] = acc3 + ffn_b[3];
    }
}

extern "C" void kernel_launch(void* const* d_in, const int* in_sizes, int n_in,
                              void* d_out, int out_size, void* d_ws, size_t ws_size,
                              hipStream_t stream) {
    const int*   chars    = (const int*)d_in[0];
    const int*   bichars  = (const int*)d_in[1];
    const int*   subwords = (const int*)d_in[2];
    const float* cw    = (const float*)d_in[3];
    const float* bw    = (const float*)d_in[4];
    const float* subw  = (const float*)d_in[5];
    const float* prew  = (const float*)d_in[6];
    const float* Wih_f = (const float*)d_in[7];
    const float* Whh_f = (const float*)d_in[8];
    const float* b_f   = (const float*)d_in[9];
    const float* Wih_b = (const float*)d_in[10];
    const float* Whh_b = (const float*)d_in[11];
    const float* b_b   = (const float*)d_in[12];
    const float* ffn_w = (const float*)d_in[13];
    const float* ffn_b = (const float*)d_in[14];
    float* out = (float*)d_out;

    float* ws = (float*)d_ws;
    float* WihT_f = ws;                      // 160000 floats each
    float* WihT_b = WihT_f + 160000;
    float* xgf = WihT_b + 160000;            // 13,107,200
    float* xgb = xgf + 13107200;             // 13,107,200
    float* hf  = xgb + 13107200;             // 3,276,800
    float* hb  = hf + 3276800;               // 3,276,800 (contiguous with hf)

    // NaN-fill h buffers (one fused memset: hf|hb contiguous) — the data
    // word itself is the readiness flag for the lstm spin-sync.
    (void)hipMemsetAsync(hf, 0xFF, 2 * 3276800 * sizeof(float), stream);
    transpose_k<<<625, 256, 0, stream>>>(Wih_f, WihT_f);
    transpose_k<<<625, 256, 0, stream>>>(Wih_b, WihT_b);
    xg_k<<<dim3(B * S / 16, 2), 256, 0, stream>>>(chars, bichars, cw, bw,
                                                  WihT_f, b_f, WihT_b, b_b, xgf, xgb);
    lstm_k<<<256, 1024, 0, stream>>>(xgf, xgb, Whh_f, Whh_b, hf, hb);
    out_k<<<(B * SK * W) / 4, 256, 0, stream>>>(subwords, prew, subw, hf, hb, ffn_w, ffn_b, out);
}

// Round 18
// 1192.662 us; speedup vs baseline: 1.4942x; 1.0399x over previous
//
#include <hip/hip_runtime.h>
#include <hip/hip_bf16.h>
#include <math.h>

#define B 32
#define S 512
#define W 8
#define CE 100       // CHAR_EMB
#define SE 100       // SUB_EMB
#define HD 200       // hidden per direction
#define G4 800       // 4*HD
#define IN2 200      // 2*CHAR_EMB
#define SUBV 100000
#define UNK 1
#define NL 4
#define SK (S - 2)   // 510
#define FEAT 500     // 2*HD + SE

typedef _Float16 h2_t __attribute__((ext_vector_type(2)));

__device__ __forceinline__ float fsig(float x) {
    return 1.f / (1.f + __expf(-x));
}
__device__ __forceinline__ float ftanh(float x) {
    float e = __expf(-2.f * fabsf(x));   // e in (0,1], overflow-safe
    float r = (1.f - e) / (1.f + e);
    return copysignf(r, x);
}

// 64-lane sum; result valid in lane 63. DPP adds run on the VALU pipe.
__device__ __forceinline__ float wave_sum64(float v) {
#if __has_builtin(__builtin_amdgcn_update_dpp)
#define DPPADD(C) { int x_ = __builtin_amdgcn_update_dpp(0, __float_as_int(v), C, 0xf, 0xf, true); \
                    v += __int_as_float(x_); }
    DPPADD(0x111)  // row_shr:1
    DPPADD(0x112)  // row_shr:2
    DPPADD(0x114)  // row_shr:4
    DPPADD(0x118)  // row_shr:8  -> lane15/31/47/63 hold row sums
    DPPADD(0x142)  // row_bcast15 -> lane31 = rows0+1, lane63 = rows2+3
    DPPADD(0x143)  // row_bcast31 -> lane63 = total
#undef DPPADD
    return v;
#else
    v += __shfl_xor(v, 1);  v += __shfl_xor(v, 2);  v += __shfl_xor(v, 4);
    v += __shfl_xor(v, 8);  v += __shfl_xor(v, 16); v += __shfl_xor(v, 32);
    return v;
#endif
}

__device__ __forceinline__ float dot4(float4 w, float4 h) {
    return fmaf(w.w, h.w, fmaf(w.z, h.z, fmaf(w.y, h.y, w.x * h.x)));
}

// packed-f16 2-way dot with f32 accumulate (v_dot2_f32_f16)
__device__ __forceinline__ float dot2f(unsigned a, unsigned b, float c) {
#if __has_builtin(__builtin_amdgcn_fdot2)
    return __builtin_amdgcn_fdot2(__builtin_bit_cast(h2_t, a),
                                  __builtin_bit_cast(h2_t, b), c, false);
#else
    h2_t x = __builtin_bit_cast(h2_t, a);
    h2_t y = __builtin_bit_cast(h2_t, b);
    return c + (float)x[0] * (float)y[0] + (float)x[1] * (float)y[1];
#endif
}

// ------- K0: transpose + pack f16: Wih[800][200] -> WTh[100][800] u32 ----
// WTh[k2][g] = half2(W[g][2k2], W[g][2k2+1])
__global__ void transpose_pack_k(const float* __restrict__ in, unsigned* __restrict__ out) {
    int o = blockIdx.x * 256 + threadIdx.x;   // 80000 elements
    if (o >= 100 * G4) return;
    int k2 = o / G4, g = o % G4;
    h2_t v;
    v[0] = (_Float16)in[g * 200 + 2 * k2];
    v[1] = (_Float16)in[g * 200 + 2 * k2 + 1];
    out[o] = __builtin_bit_cast(unsigned, v);
}

// ---------------- K2: fused embed + xg via v_dot2_f32_f16 ----------------
// Stages the 16-row x-tile as packed f16 pairs gathered straight from the
// embedding tables; inner loop does 2 MACs per instruction (f32 accum).
__global__ void xg_k(const int* __restrict__ chars, const int* __restrict__ bichars,
                     const float* __restrict__ cw, const float* __restrict__ bw,
                     const unsigned* __restrict__ WTh_f, const float* __restrict__ bf,
                     const unsigned* __restrict__ WTh_b, const float* __restrict__ bb,
                     float* __restrict__ xgf, float* __restrict__ xgb) {
    const int dir = blockIdx.y;
    const unsigned* WT = dir ? WTh_b : WTh_f;
    const float* bias  = dir ? bb : bf;
    float* out         = dir ? xgb : xgf;
    int r0 = blockIdx.x * 16;
    __shared__ unsigned xs2[16][100];
    for (int i = threadIdx.x; i < 16 * 100; i += 256) {
        int r = i / 100, c2 = i % 100;
        int row = r0 + r;                         // flat token index b*S+s
        float a, b;
        if (c2 < 50) {
            const float* p = cw + (size_t)chars[row] * CE + 2 * c2;
            a = p[0]; b = p[1];
        } else {
            const float* p = bw + (size_t)bichars[row] * CE + 2 * (c2 - 50);
            a = p[0]; b = p[1];
        }
        h2_t v; v[0] = (_Float16)a; v[1] = (_Float16)b;
        xs2[r][c2] = __builtin_bit_cast(unsigned, v);
    }
    __syncthreads();
    float acc[4][16];
    for (int q = 0; q < 4; q++)
        for (int r = 0; r < 16; r++) acc[q][r] = 0.f;
    int tid = threadIdx.x;
    for (int k2 = 0; k2 < 100; k2++) {
        const unsigned* wrow = WT + (size_t)k2 * G4;
        unsigned w0 = wrow[tid];
        unsigned w1 = wrow[tid + 256];
        unsigned w2 = wrow[tid + 512];
        unsigned w3 = (tid < 32) ? wrow[tid + 768] : 0u;
        for (int r = 0; r < 16; r++) {
            unsigned xv = xs2[r][k2];
            acc[0][r] = dot2f(w0, xv, acc[0][r]);
            acc[1][r] = dot2f(w1, xv, acc[1][r]);
            acc[2][r] = dot2f(w2, xv, acc[2][r]);
            acc[3][r] = dot2f(w3, xv, acc[3][r]);
        }
    }
    for (int q = 0; q < 4; q++) {
        int g = tid + q * 256;
        if (g < G4) {
            float bv = bias[g];
            for (int r = 0; r < 16; r++)
                out[(size_t)(r0 + r) * G4 + g] = acc[q][r] + bv;
        }
    }
}

// ---------------- K3: LSTM recurrence, merged 2-barrier superphases ------
// EXACT r13 structure (981us proven): grid = 256 blocks = 8 slices x
// (2 dirs x 16 pairs); blk = sl*32 + pg keeps all 8 slices of a pair-chain
// on one XCD (XCD = blk%8 = pg%8). T=1024. Per step: TWO superphases, ONE
// barrier each.
//  SP0(s): wave15 acts B(s-1) FIRST (h store early in phase); waves 0-14
//          compute A(s) dense from hsA; fill lanes (t<200, foreign slice)
//          poll h_B(s-1) AFTER their compute. One barrier.
//  SP1(s): symmetric: act A(s); compute B(s); fill h_A(s) -> hsA for s+1.
// Data-flag sync: hout NaN-filled per launch; write-once addresses.
__global__ __launch_bounds__(1024)
void lstm_k(const float* __restrict__ xgf, const float* __restrict__ xgb,
            const float* __restrict__ Whh_f, const float* __restrict__ Whh_b,
            float* __restrict__ hf, float* __restrict__ hb) {
    __shared__ float4 wlds[5064];                 // [col*50+l]; pad for lane>=50
    __shared__ __align__(16) float hsA[256];
    __shared__ __align__(16) float hsB[256];
    __shared__ __align__(16) float gbA[112];      // [gate*25 + unit]
    __shared__ __align__(16) float gbB[112];

    const int blk = blockIdx.x;
    const int sl  = blk >> 5;                     // slice 0..7 (25 units)
    const int pg  = blk & 31;                     // dir*16 + pair
    const int dir = pg >> 4;
    const int bA  = pg & 15;
    const int bB  = bA + 16;
    const float* xg  = dir ? xgb : xgf;
    const float* Whh = dir ? Whh_b : Whh_f;
    float* hout      = dir ? hb : hf;

    const int t = threadIdx.x;
    const int lane = t & 63;
    const int wid = t >> 6;                       // wave id 0..15

    // stage weights: wlds[col*50+l] = Whh[row(col)][4l..4l+3]
    // col = gate*25+unit -> row = gate*200 + sl*25 + unit.
    // Slots [5000,5064): ZEROED so lane>=50 over-reads are finite (the r15
    // hang came from NaN bits in uninitialized LDS reaching the polls).
    for (int i = t; i < 5064; i += 1024) {
        float4 v = {0.f, 0.f, 0.f, 0.f};
        if (i < 5000) {
            int col = i / 50, l = i - col * 50;
            int row = (col / 25) * 200 + sl * 25 + (col % 25);
            v = *(const float4*)(Whh + (size_t)row * HD + 4 * l);
        }
        wlds[i] = v;
    }
    if (t < 256) { hsA[t] = 0.f; hsB[t] = 0.f; }

    const bool is_act = (t >= 960) && (t < 985);  // wave 15, lanes 0..24
    const int u = t - 960;
    const bool fill = (t < 200) && (t / 25 != sl);
    float cstA = 0.f, cstB = 0.f;
    float xA0=0,xA1=0,xA2=0,xA3=0, xB0=0,xB1=0,xB2=0,xB3=0;
    if (is_act) {
        int ts0 = dir ? (S - 1) : 0;
        const float* pa = xg + ((size_t)bA * S + ts0) * G4 + sl * 25 + u;
        const float* pb = xg + ((size_t)bB * S + ts0) * G4 + sl * 25 + u;
        xA0 = pa[0]; xA1 = pa[200]; xA2 = pa[400]; xA3 = pa[600];
        xB0 = pb[0]; xB1 = pb[200]; xB2 = pb[400]; xB3 = pb[600];
    }
    __syncthreads();

#define COMPUTE(hsX, gbX)                                                      \
    {                                                                          \
        float4 hv = ((const float4*)hsX)[lane];                                \
        _Pragma("unroll")                                                      \
        for (int j = 0; j < 7; j++) {                                          \
            int c = wid + 15 * j;                                              \
            if (c < 100) {                                                     \
                float4 wv = wlds[c * 50 + lane];                               \
                float a = wave_sum64(dot4(wv, hv));                            \
                if (lane == 63) gbX[c] = a;                                    \
            }                                                                  \
        }                                                                      \
    }

#define POLL(dst, srcp)                                                        \
    {                                                                          \
        float v_;                                                              \
        do { v_ = __hip_atomic_load(srcp, __ATOMIC_RELAXED,                    \
                                    __HIP_MEMORY_SCOPE_AGENT); } while (v_ != v_); \
        dst = v_;                                                              \
    }

    for (int s = 0; s < S; s++) {
        const int ts  = dir ? (S - 1 - s) : s;          // time of step s
        const int tsp = dir ? (S - s)     : (s - 1);    // time of step s-1
        const int tsn = (s + 1 < S) ? (dir ? (S - 2 - s) : (s + 1)) : ts;

        // ======== SP0: act B(s-1) | compute A(s) | fill hsB <- h_B(s-1) ====
        if (is_act && s > 0) {
            float ig = fsig(gbB[u] + xB0);
            float fg = fsig(gbB[25 + u] + xB1);
            float gt = ftanh(gbB[50 + u] + xB2);
            float og = fsig(gbB[75 + u] + xB3);
            cstB = fg * cstB + ig * gt;
            float h = og * ftanh(cstB);
            hsB[sl * 25 + u] = h;
            __hip_atomic_store(&hout[((size_t)bB * S + tsp) * HD + sl * 25 + u], h,
                               __ATOMIC_RELAXED, __HIP_MEMORY_SCOPE_AGENT);
            const float* pn = xg + ((size_t)bB * S + ts) * G4 + sl * 25 + u;
            xB0 = pn[0]; xB1 = pn[200]; xB2 = pn[400]; xB3 = pn[600];
        }
        if (wid < 15) COMPUTE(hsA, gbA)
        if (s > 0 && fill) POLL(hsB[t], hout + ((size_t)bB * S + tsp) * HD + t)
        __syncthreads();

        // ======== SP1: act A(s) | compute B(s) | fill hsA <- h_A(s) ========
        if (is_act) {
            float ig = fsig(gbA[u] + xA0);
            float fg = fsig(gbA[25 + u] + xA1);
            float gt = ftanh(gbA[50 + u] + xA2);
            float og = fsig(gbA[75 + u] + xA3);
            cstA = fg * cstA + ig * gt;
            float h = og * ftanh(cstA);
            hsA[sl * 25 + u] = h;
            __hip_atomic_store(&hout[((size_t)bA * S + ts) * HD + sl * 25 + u], h,
                               __ATOMIC_RELAXED, __HIP_MEMORY_SCOPE_AGENT);
            const float* pn = xg + ((size_t)bA * S + tsn) * G4 + sl * 25 + u;
            xA0 = pn[0]; xA1 = pn[200]; xA2 = pn[400]; xA3 = pn[600];
        }
        if (wid < 15) COMPUTE(hsB, gbB)
        if (fill) POLL(hsA[t], hout + ((size_t)bA * S + ts) * HD + t)
        __syncthreads();
    }
    // epilogue: act B(S-1) (gbB from SP1(S-1), xB prefetched in SP0(S-1))
    if (is_act) {
        const int tl = dir ? 0 : (S - 1);
        float ig = fsig(gbB[u] + xB0);
        float fg = fsig(gbB[25 + u] + xB1);
        float gt = ftanh(gbB[50 + u] + xB2);
        float og = fsig(gbB[75 + u] + xB3);
        cstB = fg * cstB + ig * gt;
        float h = og * ftanh(cstB);
        __hip_atomic_store(&hout[((size_t)bB * S + tl) * HD + sl * 25 + u], h,
                           __ATOMIC_RELAXED, __HIP_MEMORY_SCOPE_AGENT);
    }
#undef COMPUTE
#undef POLL
}

// ---------------- K4: span features + subword emb + FFN ----------------
__global__ void out_k(const int* __restrict__ subwords,
                      const float* __restrict__ pre_w, const float* __restrict__ sub_w,
                      const float* __restrict__ hf, const float* __restrict__ hb,
                      const float* __restrict__ ffn_w, const float* __restrict__ ffn_b,
                      float* __restrict__ out) {
    int wave = (blockIdx.x * 256 + threadIdx.x) >> 6;
    int lane = threadIdx.x & 63;
    if (wave >= B * SK * W) return;
    int i = wave % W;
    int bk = wave / W;
    int k = bk % SK;
    int b = bk / SK;
    int end = k + i;
    float vscale = (end <= S - 3) ? 1.f : 0.f;
    int e1 = min(end + 1, S - 1);
    int e2 = min(end + 2, S - 1);
    const float* hfb = hf + (size_t)b * S * HD;
    const float* hbb = hb + (size_t)b * S * HD;
    int sw = subwords[wave];
    int sw2 = (sw >= SUBV) ? UNK : sw;
    float acc0 = 0, acc1 = 0, acc2 = 0, acc3 = 0;
    for (int j = lane; j < FEAT; j += 64) {
        float fv;
        if (j < HD) {
            fv = (hfb[(size_t)e1 * HD + j] - hfb[(size_t)k * HD + j]) * vscale;
        } else if (j < 2 * HD) {
            int jj = j - HD;
            fv = (hbb[(size_t)(k + 1) * HD + jj] - hbb[(size_t)e2 * HD + jj]) * vscale;
        } else {
            int jj = j - 2 * HD;
            fv = pre_w[(size_t)sw * SE + jj] + sub_w[(size_t)sw2 * SE + jj];
        }
        acc0 += ffn_w[j] * fv;
        acc1 += ffn_w[FEAT + j] * fv;
        acc2 += ffn_w[2 * FEAT + j] * fv;
        acc3 += ffn_w[3 * FEAT + j] * fv;
    }
    for (int off = 32; off; off >>= 1) {
        acc0 += __shfl_down(acc0, off);
        acc1 += __shfl_down(acc1, off);
        acc2 += __shfl_down(acc2, off);
        acc3 += __shfl_down(acc3, off);
    }
    if (lane == 0) {
        float* o = out + (size_t)wave * NL;
        o[0] = acc0 + ffn_b[0];
        o[1] = acc1 + ffn_b[1];
        o[2] = acc2 + ffn_b[2];
        o[3] = acc3 + ffn_b[3];
    }
}

extern "C" void kernel_launch(void* const* d_in, const int* in_sizes, int n_in,
                              void* d_out, int out_size, void* d_ws, size_t ws_size,
                              hipStream_t stream) {
    const int*   chars    = (const int*)d_in[0];
    const int*   bichars  = (const int*)d_in[1];
    const int*   subwords = (const int*)d_in[2];
    const float* cw    = (const float*)d_in[3];
    const float* bw    = (const float*)d_in[4];
    const float* subw  = (const float*)d_in[5];
    const float* prew  = (const float*)d_in[6];
    const float* Wih_f = (const float*)d_in[7];
    const float* Whh_f = (const float*)d_in[8];
    const float* b_f   = (const float*)d_in[9];
    const float* Wih_b = (const float*)d_in[10];
    const float* Whh_b = (const float*)d_in[11];
    const float* b_b   = (const float*)d_in[12];
    const float* ffn_w = (const float*)d_in[13];
    const float* ffn_b = (const float*)d_in[14];
    float* out = (float*)d_out;

    float* ws = (float*)d_ws;
    unsigned* WTh_f = (unsigned*)ws;         // 80000 u32 each (packed f16)
    unsigned* WTh_b = WTh_f + 80000;
    float* xgf = (float*)(WTh_b + 80000);    // 13,107,200
    float* xgb = xgf + 13107200;             // 13,107,200
    float* hf  = xgb + 13107200;             // 3,276,800
    float* hb  = hf + 3276800;               // 3,276,800 (contiguous with hf)

    // NaN-fill h buffers (one fused memset: hf|hb contiguous) — the data
    // word itself is the readiness flag for the lstm spin-sync.
    (void)hipMemsetAsync(hf, 0xFF, 2 * 3276800 * sizeof(float), stream);
    transpose_pack_k<<<313, 256, 0, stream>>>(Wih_f, WTh_f);
    transpose_pack_k<<<313, 256, 0, stream>>>(Wih_b, WTh_b);
    xg_k<<<dim3(B * S / 16, 2), 256, 0, stream>>>(chars, bichars, cw, bw,
                                                  WTh_f, b_f, WTh_b, b_b, xgf, xgb);
    lstm_k<<<256, 1024, 0, stream>>>(xgf, xgb, Whh_f, Whh_b, hf, hb);
    out_k<<<(B * SK * W) / 4, 256, 0, stream>>>(subwords, prew, subw, hf, hb, ffn_w, ffn_b, out);
}